// Round 7
// baseline (1039.182 us; speedup 1.0000x reference)
//
#include <hip/hip_runtime.h>
#include <math.h>

// Problem constants
#define BB 4
#define SS 64
#define NN 256
#define FF 32
#define HH 64
#define MM (BB*SS)      // 256 graphs
#define NSEQ (BB*NN)    // 1024 sequences
#define TT SS           // 64 timesteps
#define MROWS (NSEQ*TT) // 65536 GEMM rows

__device__ __forceinline__ float sigmoid_f(float x) { return 1.0f / (1.0f + __expf(-x)); }
__device__ __forceinline__ float tanh_f(float x) {
    float t = __expf(-2.0f * fabsf(x));
    float r = (1.0f - t) / (1.0f + t);
    return copysignf(r, x);
}

// Pin a float in a VGPR: asm-defined values are not rematerializable.
// NOTE (R6 lesson): pinning only works if total demand < 256 architected
// VGPRs — above that the RA spills the pinned values to scratch (L2-backed),
// which is exactly as slow as remat. Keep per-lane pinned state <= ~100.
#define KEEP_V(x) asm volatile("" : "+v"(x))

// ---------------------------------------------------------------------------
// GAT layer: one block per graph, fused softmax-staging + 8x8 register GEMM.
// (unchanged)
// ---------------------------------------------------------------------------
template<int FIN>
__global__ __launch_bounds__(256) void gat_kernel(
    const float* __restrict__ xin,   // [M][N][FIN]
    const float* __restrict__ adj,   // [M][N][N]
    const float* __restrict__ W,     // [FIN][64]
    const float* __restrict__ a,     // [128]
    const float* __restrict__ gamma_, const float* __restrict__ beta_,
    float* __restrict__ gout)        // [M][N][64]
{
    constexpr int HP = 68;
    constexpr int KC = 32;
    constexpr int PP = 260;
    __shared__ __align__(16) float h_lds[256 * HP];
    __shared__ __align__(16) float p_s[2][KC * PP];
    __shared__ float s1[256], s2[256], srow[256];

    const int m = blockIdx.x;
    const int tid = threadIdx.x;
    const int c = tid & 63;
    const int w = tid >> 6;

    {
        float wreg[FIN];
#pragma unroll
        for (int f = 0; f < FIN; ++f) wreg[f] = W[f * 64 + c];
        const float* xm = xin + (size_t)m * NN * FIN;
        for (int i0 = 0; i0 < 64; ++i0) {
            int i = (i0 << 2) | w;
            float acc = 0.0f;
#pragma unroll
            for (int f4 = 0; f4 < FIN / 4; ++f4) {
                float4 xv = *(const float4*)&xm[i * FIN + f4 * 4];
                acc += xv.x * wreg[f4*4] + xv.y * wreg[f4*4+1]
                     + xv.z * wreg[f4*4+2] + xv.w * wreg[f4*4+3];
            }
            h_lds[i * HP + c] = acc;
        }
    }
    __syncthreads();

    {
        float acc1 = 0.0f, acc2 = 0.0f;
        const float* hr = &h_lds[tid * HP];
#pragma unroll
        for (int c4 = 0; c4 < 16; ++c4) {
            float4 hv  = *(const float4*)&hr[c4 * 4];
            float4 av1 = *(const float4*)&a[c4 * 4];
            float4 av2 = *(const float4*)&a[64 + c4 * 4];
            acc1 += hv.x * av1.x + hv.y * av1.y + hv.z * av1.z + hv.w * av1.w;
            acc2 += hv.x * av2.x + hv.y * av2.y + hv.z * av2.z + hv.w * av2.w;
        }
        s1[tid] = acc1; s2[tid] = acc2;
    }
    __syncthreads();

    const float* adjr = adj + ((size_t)m * NN + tid) * NN;
    const int ty = tid >> 3;
    const int tx = tid & 7;
    const float s1v = s1[tid];

    float4 areg[8];
    float srow_acc = 0.0f;
    float acc[8][8];
#pragma unroll
    for (int r = 0; r < 8; ++r)
#pragma unroll
        for (int q = 0; q < 8; ++q) acc[r][q] = 0.0f;

    auto load_chunk = [&](int ch) {
#pragma unroll
        for (int q = 0; q < 8; ++q)
            areg[q] = *(const float4*)&adjr[ch * KC + q * 4];
    };
    auto make_p = [&](int ch, int buf) {
        float s2r[KC];
#pragma unroll
        for (int q = 0; q < 8; ++q) {
            float4 sv = *(const float4*)&s2[ch * KC + q * 4];
            s2r[q*4+0] = sv.x; s2r[q*4+1] = sv.y; s2r[q*4+2] = sv.z; s2r[q*4+3] = sv.w;
        }
        const float* af = (const float*)areg;
#pragma unroll
        for (int kk = 0; kk < KC; ++kk) {
            float e = s1v + s2r[kk];
            e = (e > 0.0f) ? e : 0.2f * e;
            float p = (af[kk] > 0.0f) ? __expf(e) : 0.0f;
            srow_acc += p;
            p_s[buf][kk * PP + tid] = p;
        }
    };

    load_chunk(0);
    make_p(0, 0);
    __syncthreads();

    for (int ch = 0; ch < 8; ++ch) {
        if (ch < 7) load_chunk(ch + 1);
        {
            const float* pb = p_s[ch & 1];
            const int jb = ch * KC;
#pragma unroll 4
            for (int kk = 0; kk < KC; ++kk) {
                const float* pk = &pb[kk * PP + ty * 8];
                float4 p0 = *(const float4*)pk;
                float4 p1 = *(const float4*)(pk + 4);
                const float* hk = &h_lds[(jb + kk) * HP + tx * 8];
                float4 h0 = *(const float4*)hk;
                float4 h1 = *(const float4*)(hk + 4);
                float pv[8] = {p0.x,p0.y,p0.z,p0.w, p1.x,p1.y,p1.z,p1.w};
                float hv[8] = {h0.x,h0.y,h0.z,h0.w, h1.x,h1.y,h1.z,h1.w};
#pragma unroll
                for (int r = 0; r < 8; ++r)
#pragma unroll
                    for (int q = 0; q < 8; ++q)
                        acc[r][q] += pv[r] * hv[q];
            }
        }
        if (ch < 7) make_p(ch + 1, (ch + 1) & 1);
        else        srow[tid] = srow_acc;
        __syncthreads();
    }

    const int i0 = ty * 8;
    float4 sr0 = *(const float4*)&srow[i0];
    float4 sr1 = *(const float4*)&srow[i0 + 4];
    float rinv[8] = {1.0f/sr0.x, 1.0f/sr0.y, 1.0f/sr0.z, 1.0f/sr0.w,
                     1.0f/sr1.x, 1.0f/sr1.y, 1.0f/sr1.z, 1.0f/sr1.w};
    float4 gm0 = *(const float4*)&gamma_[tx * 8];
    float4 gm1 = *(const float4*)&gamma_[tx * 8 + 4];
    float4 bt0 = *(const float4*)&beta_[tx * 8];
    float4 bt1 = *(const float4*)&beta_[tx * 8 + 4];
    float gm[8] = {gm0.x,gm0.y,gm0.z,gm0.w, gm1.x,gm1.y,gm1.z,gm1.w};
    float bt[8] = {bt0.x,bt0.y,bt0.z,bt0.w, bt1.x,bt1.y,bt1.z,bt1.w};

#pragma unroll
    for (int r = 0; r < 8; ++r) {
        float v[8];
        float sm = 0.0f, sq = 0.0f;
#pragma unroll
        for (int q = 0; q < 8; ++q) {
            v[q] = acc[r][q] * rinv[r];
            sm += v[q]; sq += v[q] * v[q];
        }
#pragma unroll
        for (int off = 1; off < 8; off <<= 1) {
            sm += __shfl_xor(sm, off);
            sq += __shfl_xor(sq, off);
        }
        float mu  = sm * (1.0f / 64.0f);
        float var = sq * (1.0f / 64.0f) - mu * mu;
        float rs  = rsqrtf(var + 1e-5f);
        float o[8];
#pragma unroll
        for (int q = 0; q < 8; ++q) {
            float hn = (v[q] - mu) * rs * gm[q] + bt[q];
            o[q] = (hn > 0.0f) ? hn : (__expf(hn) - 1.0f);
        }
        float* gp = &gout[((size_t)m * NN + i0 + r) * 64 + tx * 8];
        *(float4*)gp       = make_float4(o[0], o[1], o[2], o[3]);
        *(float4*)(gp + 4) = make_float4(o[4], o[5], o[6], o[7]);
    }
}

// ---------------------------------------------------------------------------
// residual + gate*g, reshaped to sequence layout [B*N][T][H]
// ---------------------------------------------------------------------------
__global__ __launch_bounds__(256) void combine_kernel(
    const float* __restrict__ x,      // [B*S*N][32]
    const float* __restrict__ g1,     // [B*S*N][64]
    const float* __restrict__ res_W,  // [32][64]
    const float* __restrict__ res_b,  // [64]
    const float* __restrict__ alpha_p,
    float* __restrict__ seqout)       // [B*N][T][64]
{
    int row = blockIdx.x * 4 + (threadIdx.x >> 6);
    int h = threadIdx.x & 63;
    int mg = row >> 8, n = row & 255;
    int b = mg >> 6, s = mg & 63;
    const float* xr = x + (size_t)row * 32;
    float acc = res_b[h];
#pragma unroll
    for (int f4 = 0; f4 < 8; ++f4) {
        float4 xv = *(const float4*)&xr[f4 * 4];
        acc += xv.x * res_W[(f4*4    ) * 64 + h] + xv.y * res_W[(f4*4 + 1) * 64 + h]
             + xv.z * res_W[(f4*4 + 2) * 64 + h] + xv.w * res_W[(f4*4 + 3) * 64 + h];
    }
    float alpha = fminf(fmaxf(alpha_p[0], 0.0f), 1.0f);
    acc += alpha * g1[(size_t)row * 64 + h];
    seqout[(((size_t)(b * NN + n)) * TT + s) * 64 + h] = acc;
}

// ---------------------------------------------------------------------------
// xg GEMM v3: conflict-free LDS access. (unchanged)
// grid: (MROWS/256, 2, 2)
// ---------------------------------------------------------------------------
template<int K>
__global__ __launch_bounds__(256, 2) void xg_gemm_kernel(
    const float* __restrict__ A,     // [65536][K]
    const float* __restrict__ Wih,   // [2][K][256]
    const float* __restrict__ bih,   // [2][256]
    const float* __restrict__ bhh,   // [2][256]
    float* __restrict__ xg)          // [2][65536][256]
{
    constexpr int KC = 16;
    constexpr int AP = 260;
    __shared__ __align__(16) float a_s[KC * AP];
    __shared__ __align__(16) float b_s[KC * 128];

    const int tid = threadIdx.x;
    const int m0  = blockIdx.x * 256;
    const int c0  = blockIdx.y * 128;
    const int dir = blockIdx.z;

    const int tx = tid & 15;
    const int ty = tid >> 4;

    float acc[16][8];
#pragma unroll
    for (int r = 0; r < 16; ++r)
#pragma unroll
        for (int c = 0; c < 8; ++c) acc[r][c] = 0.0f;

    const float* Bd = Wih + (size_t)dir * K * 256;

    for (int kc = 0; kc < K; kc += KC) {
#pragma unroll
        for (int i = 0; i < 4; ++i) {
            int idx = tid + i * 256;
            int row = idx >> 2, k4 = (idx & 3) << 2;
            float4 v = *(const float4*)&A[(size_t)(m0 + row) * K + kc + k4];
            a_s[(k4 + 0) * AP + row] = v.x;
            a_s[(k4 + 1) * AP + row] = v.y;
            a_s[(k4 + 2) * AP + row] = v.z;
            a_s[(k4 + 3) * AP + row] = v.w;
        }
#pragma unroll
        for (int i = 0; i < 2; ++i) {
            int idx = tid + i * 256;
            int kr = idx >> 5, c4 = (idx & 31) << 2;
            *(float4*)&b_s[kr * 128 + c4] =
                *(const float4*)&Bd[(size_t)(kc + kr) * 256 + c0 + c4];
        }
        __syncthreads();

#pragma unroll 4
        for (int k = 0; k < KC; ++k) {
            const float* ak = &a_s[k * AP + ty * 16];
            float4 a0 = *(const float4*)&ak[0];
            float4 a1 = *(const float4*)&ak[4];
            float4 a2 = *(const float4*)&ak[8];
            float4 a3 = *(const float4*)&ak[12];
            float4 b0 = *(const float4*)&b_s[k * 128 + tx * 4];
            float4 b1 = *(const float4*)&b_s[k * 128 + 64 + tx * 4];
            float av[16] = {a0.x,a0.y,a0.z,a0.w, a1.x,a1.y,a1.z,a1.w,
                            a2.x,a2.y,a2.z,a2.w, a3.x,a3.y,a3.z,a3.w};
            float bv[8]  = {b0.x,b0.y,b0.z,b0.w, b1.x,b1.y,b1.z,b1.w};
#pragma unroll
            for (int r = 0; r < 16; ++r)
#pragma unroll
                for (int c = 0; c < 8; ++c)
                    acc[r][c] += av[r] * bv[c];
        }
        __syncthreads();
    }

    float4 b1v = *(const float4*)&bih[dir * 256 + c0 + tx * 4];
    float4 b2v = *(const float4*)&bhh[dir * 256 + c0 + tx * 4];
    float4 b1w = *(const float4*)&bih[dir * 256 + c0 + 64 + tx * 4];
    float4 b2w = *(const float4*)&bhh[dir * 256 + c0 + 64 + tx * 4];
    float4 biasA = make_float4(b1v.x + b2v.x, b1v.y + b2v.y, b1v.z + b2v.z, b1v.w + b2v.w);
    float4 biasB = make_float4(b1w.x + b2w.x, b1w.y + b2w.y, b1w.z + b2w.z, b1w.w + b2w.w);
    float* out = xg + (size_t)dir * MROWS * 256;
#pragma unroll
    for (int r = 0; r < 16; ++r) {
        size_t o = (size_t)(m0 + ty * 16 + r) * 256 + c0 + tx * 4;
        float4 v0 = make_float4(acc[r][0] + biasA.x, acc[r][1] + biasA.y,
                                acc[r][2] + biasA.z, acc[r][3] + biasA.w);
        float4 v1 = make_float4(acc[r][4] + biasB.x, acc[r][5] + biasB.y,
                                acc[r][6] + biasB.z, acc[r][7] + biasB.w);
        *(float4*)&out[o]      = v0;
        *(float4*)&out[o + 64] = v1;
    }
}

// ---------------------------------------------------------------------------
// LSTM recurrence v4: SEQUENCE-BATCHED weight reuse.
// One block = 4 sequences of the SAME direction (they share Whh[dir]).
// Thread k (0..255) owns gate k and holds only w[64] = Whh[dir][:,k] in
// VGPRs (~100 total, safely under the 256 architected ceiling that killed
// v2/v3 via scratch spill). Each weight is reused across 4 sequences.
// Phase 1 (per step): thread computes gate k for all 4 seqs; h read from LDS
//   with wave-uniform b128 reads (broadcast = free on the DS pipe).
//   Activation branch is wave-uniform (waves 0,1,3 sigmoid; wave 2 tanh).
// Phase 2: thread (s,u) owns c[s][u]; updates c, h; writes h to LDS+global.
// 2 barriers/step. grid: 512 blocks (b>>8 = dir, (b&255)*4 = seq base).
// ---------------------------------------------------------------------------
__global__ __launch_bounds__(256, 2) void lstm_batch_kernel(
    const float* __restrict__ xg,    // [2][NSEQ][T][256] natural t order
    const float* __restrict__ Whh,   // [2][64][256]
    float* __restrict__ out,         // write_all: o1 [NSEQ][T][128]; else [NSEQ][128]
    int write_all)
{
    const int tid  = threadIdx.x;
    const int dir  = blockIdx.x >> 8;
    const int seq0 = (blockIdx.x & 255) * 4;

    // weight column for gate `tid` (coalesced across threads per j)
    float w[64];
    const float* Wd = Whh + (size_t)dir * 64 * 256 + tid;
#pragma unroll
    for (int j = 0; j < 64; ++j) w[j] = Wd[j * 256];
#pragma unroll
    for (int j = 0; j < 64; ++j) KEEP_V(w[j]);

    __shared__ __align__(16) float h_s[4][64];
    __shared__ float gbuf[4][256];
    ((float*)h_s)[tid] = 0.0f;
    float c = 0.0f;
    const int su = tid >> 6, uu = tid & 63;   // phase-2 ownership

    const float* xgb = xg + ((size_t)dir * NSEQ + seq0) * TT * 256;
    const int t0 = dir ? (TT - 1) : 0;
    float xr[4];
#pragma unroll
    for (int s = 0; s < 4; ++s)
        xr[s] = xgb[((size_t)s * TT + t0) * 256 + tid];
    __syncthreads();

    for (int step = 0; step < TT; ++step) {
        // note: for dir=1, read-time and write-time coincide (t = TT-1-step)
        const int t = dir ? (TT - 1 - step) : step;
        float acc0 = xr[0], acc1 = xr[1], acc2 = xr[2], acc3 = xr[3];
        if (step + 1 < TT) {                  // prefetch next step's xg
            int tn = dir ? (TT - 2 - step) : (step + 1);
#pragma unroll
            for (int s = 0; s < 4; ++s)
                xr[s] = xgb[((size_t)s * TT + tn) * 256 + tid];
        }
#pragma unroll
        for (int j4 = 0; j4 < 16; ++j4) {
            float4 h0 = *(const float4*)&h_s[0][j4 * 4];
            float4 h1 = *(const float4*)&h_s[1][j4 * 4];
            float4 h2 = *(const float4*)&h_s[2][j4 * 4];
            float4 h3 = *(const float4*)&h_s[3][j4 * 4];
            float w0 = w[j4*4], w1 = w[j4*4+1], w2 = w[j4*4+2], w3 = w[j4*4+3];
            acc0 += h0.x*w0 + h0.y*w1 + h0.z*w2 + h0.w*w3;
            acc1 += h1.x*w0 + h1.y*w1 + h1.z*w2 + h1.w*w3;
            acc2 += h2.x*w0 + h2.y*w1 + h2.z*w2 + h2.w*w3;
            acc3 += h3.x*w0 + h3.y*w1 + h3.z*w2 + h3.w*w3;
        }
        const bool sig = (tid < 128) || (tid >= 192);   // wave-uniform
        gbuf[0][tid] = sig ? sigmoid_f(acc0) : tanh_f(acc0);
        gbuf[1][tid] = sig ? sigmoid_f(acc1) : tanh_f(acc1);
        gbuf[2][tid] = sig ? sigmoid_f(acc2) : tanh_f(acc2);
        gbuf[3][tid] = sig ? sigmoid_f(acc3) : tanh_f(acc3);
        __syncthreads();

        // phase 2: thread (su,uu) owns cell state c
        float iv = gbuf[su][uu], fv = gbuf[su][64 + uu];
        float gv = gbuf[su][128 + uu], ov = gbuf[su][192 + uu];
        c = fv * c + iv * gv;
        float h = ov * tanh_f(c);
        h_s[su][uu] = h;
        if (write_all) {
            out[((size_t)(seq0 + su) * TT + t) * 128 + dir * 64 + uu] = h;
        } else if (step == TT - 1) {
            out[(size_t)(seq0 + su) * 128 + dir * 64 + uu] = h;
        }
        __syncthreads();
    }
}

// ---------------------------------------------------------------------------
__global__ __launch_bounds__(256) void fc_kernel(
    const float* __restrict__ fin,   // [NSEQ][128]
    const float* __restrict__ fc_W,  // [128]
    const float* __restrict__ fc_b,  // [1]
    float* __restrict__ outp)        // [NSEQ]
{
    int s = blockIdx.x * 256 + threadIdx.x;
    const float* fr = fin + (size_t)s * 128;
    float acc = fc_b[0];
#pragma unroll
    for (int k4 = 0; k4 < 32; ++k4) {
        float4 fv = *(const float4*)&fr[k4 * 4];
        float4 wv2 = *(const float4*)&fc_W[k4 * 4];
        acc += fv.x * wv2.x + fv.y * wv2.y + fv.z * wv2.z + fv.w * wv2.w;
    }
    outp[s] = acc;
}

// ---------------------------------------------------------------------------
extern "C" void kernel_launch(void* const* d_in, const int* in_sizes, int n_in,
                              void* d_out, int out_size, void* d_ws, size_t ws_size,
                              hipStream_t stream) {
    const float* x       = (const float*)d_in[0];
    const float* adj     = (const float*)d_in[1];
    const float* gat0_W  = (const float*)d_in[2];
    const float* gat0_a  = (const float*)d_in[3];
    const float* gat0_g  = (const float*)d_in[4];
    const float* gat0_b  = (const float*)d_in[5];
    const float* gat1_W  = (const float*)d_in[6];
    const float* gat1_a  = (const float*)d_in[7];
    const float* gat1_g  = (const float*)d_in[8];
    const float* gat1_b  = (const float*)d_in[9];
    const float* res_W   = (const float*)d_in[10];
    const float* res_b   = (const float*)d_in[11];
    const float* alpha_g = (const float*)d_in[12];
    const float* l0_Wih  = (const float*)d_in[13];
    const float* l0_Whh  = (const float*)d_in[14];
    const float* l0_bih  = (const float*)d_in[15];
    const float* l0_bhh  = (const float*)d_in[16];
    const float* l1_Wih  = (const float*)d_in[17];
    const float* l1_Whh  = (const float*)d_in[18];
    const float* l1_bih  = (const float*)d_in[19];
    const float* l1_bhh  = (const float*)d_in[20];
    const float* fc_W    = (const float*)d_in[21];
    const float* fc_b    = (const float*)d_in[22];

    float* ws = (float*)d_ws;
    float* g0    = ws;                    // [M][N][64]
    float* g1    = ws + 4194304;          // [M][N][64]
    float* seq   = ws + 8388608;          // [B*N][T][64]
    float* xg    = ws + 12582912;         // [2][65536][256]
    float* fin   = ws + 46137344;         // [NSEQ][128]
    float* o1    = ws;                    // reuse g0+g1 [NSEQ][T][128]

    gat_kernel<32><<<MM, 256, 0, stream>>>(x, adj, gat0_W, gat0_a, gat0_g, gat0_b, g0);
    gat_kernel<64><<<MM, 256, 0, stream>>>(g0, adj, gat1_W, gat1_a, gat1_g, gat1_b, g1);
    combine_kernel<<<(BB*SS*NN)/4, 256, 0, stream>>>(x, g1, res_W, res_b, alpha_g, seq);
    xg_gemm_kernel<64><<<dim3(MROWS/256, 2, 2), 256, 0, stream>>>(seq, l0_Wih, l0_bih, l0_bhh, xg);
    lstm_batch_kernel<<<512, 256, 0, stream>>>(xg, l0_Whh, o1, 1);
    xg_gemm_kernel<128><<<dim3(MROWS/256, 2, 2), 256, 0, stream>>>(o1, l1_Wih, l1_bih, l1_bhh, xg);
    lstm_batch_kernel<<<512, 256, 0, stream>>>(xg, l1_Whh, fin, 0);
    fc_kernel<<<NSEQ/256, 256, 0, stream>>>(fin, fc_W, fc_b, (float*)d_out);
}

// Round 8
// 823.363 us; speedup vs baseline: 1.2621x; 1.2621x over previous
//
#include <hip/hip_runtime.h>
#include <math.h>

// Problem constants
#define BB 4
#define SS 64
#define NN 256
#define FF 32
#define HH 64
#define MM (BB*SS)      // 256 graphs
#define NSEQ (BB*NN)    // 1024 sequences
#define TT SS           // 64 timesteps
#define MROWS (NSEQ*TT) // 65536 GEMM rows

__device__ __forceinline__ float sigmoid_f(float x) { return 1.0f / (1.0f + __expf(-x)); }
__device__ __forceinline__ float tanh_f(float x) {
    float t = __expf(-2.0f * fabsf(x));
    float r = (1.0f - t) / (1.0f + t);
    return copysignf(r, x);
}

// Pin a float in a VGPR (defeats load remat). Only safe when total per-lane
// demand < 256 architected VGPRs (R6: above that the RA spills pins to
// scratch, which is as slow as the remat it prevents).
#define KEEP_V(x) asm volatile("" : "+v"(x))

// Wave-wide broadcast of lane j's value via SGPR (VALU pipe, no LDS/DS).
__device__ __forceinline__ float lane_bcast(float v, int j) {
    return __int_as_float(__builtin_amdgcn_readlane(__float_as_int(v), j));
}

// ---------------------------------------------------------------------------
// GAT layer: one block per graph, fused softmax-staging + 8x8 register GEMM.
// (unchanged)
// ---------------------------------------------------------------------------
template<int FIN>
__global__ __launch_bounds__(256) void gat_kernel(
    const float* __restrict__ xin,   // [M][N][FIN]
    const float* __restrict__ adj,   // [M][N][N]
    const float* __restrict__ W,     // [FIN][64]
    const float* __restrict__ a,     // [128]
    const float* __restrict__ gamma_, const float* __restrict__ beta_,
    float* __restrict__ gout)        // [M][N][64]
{
    constexpr int HP = 68;
    constexpr int KC = 32;
    constexpr int PP = 260;
    __shared__ __align__(16) float h_lds[256 * HP];
    __shared__ __align__(16) float p_s[2][KC * PP];
    __shared__ float s1[256], s2[256], srow[256];

    const int m = blockIdx.x;
    const int tid = threadIdx.x;
    const int c = tid & 63;
    const int w = tid >> 6;

    {
        float wreg[FIN];
#pragma unroll
        for (int f = 0; f < FIN; ++f) wreg[f] = W[f * 64 + c];
        const float* xm = xin + (size_t)m * NN * FIN;
        for (int i0 = 0; i0 < 64; ++i0) {
            int i = (i0 << 2) | w;
            float acc = 0.0f;
#pragma unroll
            for (int f4 = 0; f4 < FIN / 4; ++f4) {
                float4 xv = *(const float4*)&xm[i * FIN + f4 * 4];
                acc += xv.x * wreg[f4*4] + xv.y * wreg[f4*4+1]
                     + xv.z * wreg[f4*4+2] + xv.w * wreg[f4*4+3];
            }
            h_lds[i * HP + c] = acc;
        }
    }
    __syncthreads();

    {
        float acc1 = 0.0f, acc2 = 0.0f;
        const float* hr = &h_lds[tid * HP];
#pragma unroll
        for (int c4 = 0; c4 < 16; ++c4) {
            float4 hv  = *(const float4*)&hr[c4 * 4];
            float4 av1 = *(const float4*)&a[c4 * 4];
            float4 av2 = *(const float4*)&a[64 + c4 * 4];
            acc1 += hv.x * av1.x + hv.y * av1.y + hv.z * av1.z + hv.w * av1.w;
            acc2 += hv.x * av2.x + hv.y * av2.y + hv.z * av2.z + hv.w * av2.w;
        }
        s1[tid] = acc1; s2[tid] = acc2;
    }
    __syncthreads();

    const float* adjr = adj + ((size_t)m * NN + tid) * NN;
    const int ty = tid >> 3;
    const int tx = tid & 7;
    const float s1v = s1[tid];

    float4 areg[8];
    float srow_acc = 0.0f;
    float acc[8][8];
#pragma unroll
    for (int r = 0; r < 8; ++r)
#pragma unroll
        for (int q = 0; q < 8; ++q) acc[r][q] = 0.0f;

    auto load_chunk = [&](int ch) {
#pragma unroll
        for (int q = 0; q < 8; ++q)
            areg[q] = *(const float4*)&adjr[ch * KC + q * 4];
    };
    auto make_p = [&](int ch, int buf) {
        float s2r[KC];
#pragma unroll
        for (int q = 0; q < 8; ++q) {
            float4 sv = *(const float4*)&s2[ch * KC + q * 4];
            s2r[q*4+0] = sv.x; s2r[q*4+1] = sv.y; s2r[q*4+2] = sv.z; s2r[q*4+3] = sv.w;
        }
        const float* af = (const float*)areg;
#pragma unroll
        for (int kk = 0; kk < KC; ++kk) {
            float e = s1v + s2r[kk];
            e = (e > 0.0f) ? e : 0.2f * e;
            float p = (af[kk] > 0.0f) ? __expf(e) : 0.0f;
            srow_acc += p;
            p_s[buf][kk * PP + tid] = p;
        }
    };

    load_chunk(0);
    make_p(0, 0);
    __syncthreads();

    for (int ch = 0; ch < 8; ++ch) {
        if (ch < 7) load_chunk(ch + 1);
        {
            const float* pb = p_s[ch & 1];
            const int jb = ch * KC;
#pragma unroll 4
            for (int kk = 0; kk < KC; ++kk) {
                const float* pk = &pb[kk * PP + ty * 8];
                float4 p0 = *(const float4*)pk;
                float4 p1 = *(const float4*)(pk + 4);
                const float* hk = &h_lds[(jb + kk) * HP + tx * 8];
                float4 h0 = *(const float4*)hk;
                float4 h1 = *(const float4*)(hk + 4);
                float pv[8] = {p0.x,p0.y,p0.z,p0.w, p1.x,p1.y,p1.z,p1.w};
                float hv[8] = {h0.x,h0.y,h0.z,h0.w, h1.x,h1.y,h1.z,h1.w};
#pragma unroll
                for (int r = 0; r < 8; ++r)
#pragma unroll
                    for (int q = 0; q < 8; ++q)
                        acc[r][q] += pv[r] * hv[q];
            }
        }
        if (ch < 7) make_p(ch + 1, (ch + 1) & 1);
        else        srow[tid] = srow_acc;
        __syncthreads();
    }

    const int i0 = ty * 8;
    float4 sr0 = *(const float4*)&srow[i0];
    float4 sr1 = *(const float4*)&srow[i0 + 4];
    float rinv[8] = {1.0f/sr0.x, 1.0f/sr0.y, 1.0f/sr0.z, 1.0f/sr0.w,
                     1.0f/sr1.x, 1.0f/sr1.y, 1.0f/sr1.z, 1.0f/sr1.w};
    float4 gm0 = *(const float4*)&gamma_[tx * 8];
    float4 gm1 = *(const float4*)&gamma_[tx * 8 + 4];
    float4 bt0 = *(const float4*)&beta_[tx * 8];
    float4 bt1 = *(const float4*)&beta_[tx * 8 + 4];
    float gm[8] = {gm0.x,gm0.y,gm0.z,gm0.w, gm1.x,gm1.y,gm1.z,gm1.w};
    float bt[8] = {bt0.x,bt0.y,bt0.z,bt0.w, bt1.x,bt1.y,bt1.z,bt1.w};

#pragma unroll
    for (int r = 0; r < 8; ++r) {
        float v[8];
        float sm = 0.0f, sq = 0.0f;
#pragma unroll
        for (int q = 0; q < 8; ++q) {
            v[q] = acc[r][q] * rinv[r];
            sm += v[q]; sq += v[q] * v[q];
        }
#pragma unroll
        for (int off = 1; off < 8; off <<= 1) {
            sm += __shfl_xor(sm, off);
            sq += __shfl_xor(sq, off);
        }
        float mu  = sm * (1.0f / 64.0f);
        float var = sq * (1.0f / 64.0f) - mu * mu;
        float rs  = rsqrtf(var + 1e-5f);
        float o[8];
#pragma unroll
        for (int q = 0; q < 8; ++q) {
            float hn = (v[q] - mu) * rs * gm[q] + bt[q];
            o[q] = (hn > 0.0f) ? hn : (__expf(hn) - 1.0f);
        }
        float* gp = &gout[((size_t)m * NN + i0 + r) * 64 + tx * 8];
        *(float4*)gp       = make_float4(o[0], o[1], o[2], o[3]);
        *(float4*)(gp + 4) = make_float4(o[4], o[5], o[6], o[7]);
    }
}

// ---------------------------------------------------------------------------
// residual + gate*g, reshaped to sequence layout [B*N][T][H]
// ---------------------------------------------------------------------------
__global__ __launch_bounds__(256) void combine_kernel(
    const float* __restrict__ x,      // [B*S*N][32]
    const float* __restrict__ g1,     // [B*S*N][64]
    const float* __restrict__ res_W,  // [32][64]
    const float* __restrict__ res_b,  // [64]
    const float* __restrict__ alpha_p,
    float* __restrict__ seqout)       // [B*N][T][64]
{
    int row = blockIdx.x * 4 + (threadIdx.x >> 6);
    int h = threadIdx.x & 63;
    int mg = row >> 8, n = row & 255;
    int b = mg >> 6, s = mg & 63;
    const float* xr = x + (size_t)row * 32;
    float acc = res_b[h];
#pragma unroll
    for (int f4 = 0; f4 < 8; ++f4) {
        float4 xv = *(const float4*)&xr[f4 * 4];
        acc += xv.x * res_W[(f4*4    ) * 64 + h] + xv.y * res_W[(f4*4 + 1) * 64 + h]
             + xv.z * res_W[(f4*4 + 2) * 64 + h] + xv.w * res_W[(f4*4 + 3) * 64 + h];
    }
    float alpha = fminf(fmaxf(alpha_p[0], 0.0f), 1.0f);
    acc += alpha * g1[(size_t)row * 64 + h];
    seqout[(((size_t)(b * NN + n)) * TT + s) * 64 + h] = acc;
}

// ---------------------------------------------------------------------------
// xg GEMM v3: conflict-free LDS access. (unchanged)
// grid: (MROWS/256, 2, 2)
// ---------------------------------------------------------------------------
template<int K>
__global__ __launch_bounds__(256, 2) void xg_gemm_kernel(
    const float* __restrict__ A,     // [65536][K]
    const float* __restrict__ Wih,   // [2][K][256]
    const float* __restrict__ bih,   // [2][256]
    const float* __restrict__ bhh,   // [2][256]
    float* __restrict__ xg)          // [2][65536][256]
{
    constexpr int KC = 16;
    constexpr int AP = 260;
    __shared__ __align__(16) float a_s[KC * AP];
    __shared__ __align__(16) float b_s[KC * 128];

    const int tid = threadIdx.x;
    const int m0  = blockIdx.x * 256;
    const int c0  = blockIdx.y * 128;
    const int dir = blockIdx.z;

    const int tx = tid & 15;
    const int ty = tid >> 4;

    float acc[16][8];
#pragma unroll
    for (int r = 0; r < 16; ++r)
#pragma unroll
        for (int c = 0; c < 8; ++c) acc[r][c] = 0.0f;

    const float* Bd = Wih + (size_t)dir * K * 256;

    for (int kc = 0; kc < K; kc += KC) {
#pragma unroll
        for (int i = 0; i < 4; ++i) {
            int idx = tid + i * 256;
            int row = idx >> 2, k4 = (idx & 3) << 2;
            float4 v = *(const float4*)&A[(size_t)(m0 + row) * K + kc + k4];
            a_s[(k4 + 0) * AP + row] = v.x;
            a_s[(k4 + 1) * AP + row] = v.y;
            a_s[(k4 + 2) * AP + row] = v.z;
            a_s[(k4 + 3) * AP + row] = v.w;
        }
#pragma unroll
        for (int i = 0; i < 2; ++i) {
            int idx = tid + i * 256;
            int kr = idx >> 5, c4 = (idx & 31) << 2;
            *(float4*)&b_s[kr * 128 + c4] =
                *(const float4*)&Bd[(size_t)(kc + kr) * 256 + c0 + c4];
        }
        __syncthreads();

#pragma unroll 4
        for (int k = 0; k < KC; ++k) {
            const float* ak = &a_s[k * AP + ty * 16];
            float4 a0 = *(const float4*)&ak[0];
            float4 a1 = *(const float4*)&ak[4];
            float4 a2 = *(const float4*)&ak[8];
            float4 a3 = *(const float4*)&ak[12];
            float4 b0 = *(const float4*)&b_s[k * 128 + tx * 4];
            float4 b1 = *(const float4*)&b_s[k * 128 + 64 + tx * 4];
            float av[16] = {a0.x,a0.y,a0.z,a0.w, a1.x,a1.y,a1.z,a1.w,
                            a2.x,a2.y,a2.z,a2.w, a3.x,a3.y,a3.z,a3.w};
            float bv[8]  = {b0.x,b0.y,b0.z,b0.w, b1.x,b1.y,b1.z,b1.w};
#pragma unroll
            for (int r = 0; r < 16; ++r)
#pragma unroll
                for (int c = 0; c < 8; ++c)
                    acc[r][c] += av[r] * bv[c];
        }
        __syncthreads();
    }

    float4 b1v = *(const float4*)&bih[dir * 256 + c0 + tx * 4];
    float4 b2v = *(const float4*)&bhh[dir * 256 + c0 + tx * 4];
    float4 b1w = *(const float4*)&bih[dir * 256 + c0 + 64 + tx * 4];
    float4 b2w = *(const float4*)&bhh[dir * 256 + c0 + 64 + tx * 4];
    float4 biasA = make_float4(b1v.x + b2v.x, b1v.y + b2v.y, b1v.z + b2v.z, b1v.w + b2v.w);
    float4 biasB = make_float4(b1w.x + b2w.x, b1w.y + b2w.y, b1w.z + b2w.z, b1w.w + b2w.w);
    float* out = xg + (size_t)dir * MROWS * 256;
#pragma unroll
    for (int r = 0; r < 16; ++r) {
        size_t o = (size_t)(m0 + ty * 16 + r) * 256 + c0 + tx * 4;
        float4 v0 = make_float4(acc[r][0] + biasA.x, acc[r][1] + biasA.y,
                                acc[r][2] + biasA.z, acc[r][3] + biasA.w);
        float4 v1 = make_float4(acc[r][4] + biasB.x, acc[r][5] + biasB.y,
                                acc[r][6] + biasB.z, acc[r][7] + biasB.w);
        *(float4*)&out[o]      = v0;
        *(float4*)&out[o + 64] = v1;
    }
}

// ---------------------------------------------------------------------------
// LSTM recurrence v5: readlane-broadcast, zero per-step DS for h.
// Block = 2 waves = 1 (seq,dir). Lane l owns hidden unit l. Wave 0 computes
// gate types {i,f}, wave 1 {g,o}: 128 weight floats/lane, pinned (< 256
// ceiling -> no spill; R6 lesson). Both waves redundantly maintain c[l],h[l]
// in registers; h[j] is broadcast via v_readlane (VALU pipe — eliminates the
// per-step LDS h-broadcast that made v2-v4 DS-bound). Cross-wave gate
// exchange through a double-buffered 2 KB gbuf: ONE barrier per step.
// grid: 2048 blocks x 128 threads.
// ---------------------------------------------------------------------------
__global__ __launch_bounds__(128, 2) void lstm_pair_kernel(
    const float* __restrict__ xg,    // [2][NSEQ][T][256] natural t order
    const float* __restrict__ Whh,   // [2][64][256]
    float* __restrict__ out,         // write_all: o1 [NSEQ][T][128]; else [NSEQ][128]
    int write_all)
{
    const int tid = threadIdx.x;
    const int w   = tid >> 6;        // wave: 0 -> {i,f}, 1 -> {g,o}
    const int l   = tid & 63;        // hidden unit
    const int sd  = blockIdx.x;
    const int seq = sd >> 1, dir = sd & 1;

    const int gA = w * 128 + l;       // gate index for chain A (i or g)
    const int gB = w * 128 + 64 + l;  // gate index for chain B (f or o)

    float wA[64], wB[64];
    const float* Wd = Whh + (size_t)dir * 64 * 256;
#pragma unroll
    for (int j = 0; j < 64; ++j) {
        wA[j] = Wd[j * 256 + gA];
        wB[j] = Wd[j * 256 + gB];
    }
#pragma unroll
    for (int j = 0; j < 64; ++j) { KEEP_V(wA[j]); KEEP_V(wB[j]); }

    __shared__ float gbuf[2][4][64];  // [buf][gate type][unit]

    float h = 0.0f, c = 0.0f;
    const float* xgb = xg + ((size_t)dir * NSEQ + seq) * TT * 256;
    const int t0 = dir ? (TT - 1) : 0;
    float xA = xgb[t0 * 256 + gA];
    float xB = xgb[t0 * 256 + gB];

    for (int step = 0; step < TT; ++step) {
        const int t = dir ? (TT - 1 - step) : step;
        float accA = xA, accB = xB;
        if (step + 1 < TT) {                    // prefetch next step's xg
            int tn = dir ? (TT - 2 - step) : (step + 1);
            xA = xgb[tn * 256 + gA];
            xB = xgb[tn * 256 + gB];
        }
#pragma unroll
        for (int j = 0; j < 64; ++j) {
            float hj = lane_bcast(h, j);        // v_readlane: VALU, no DS
            accA += hj * wA[j];
            accB += hj * wB[j];
        }
        // wave-uniform activation: wave0 = sig,sig (i,f); wave1 = tanh,sig (g,o)
        float vA = (w == 0) ? sigmoid_f(accA) : tanh_f(accA);
        float vB = sigmoid_f(accB);
        const int buf = step & 1;
        gbuf[buf][w * 2 + 0][l] = vA;
        gbuf[buf][w * 2 + 1][l] = vB;
        __syncthreads();
        float iv, fv, gv, ov;
        if (w == 0) { iv = vA; fv = vB; gv = gbuf[buf][2][l]; ov = gbuf[buf][3][l]; }
        else        { gv = vA; ov = vB; iv = gbuf[buf][0][l]; fv = gbuf[buf][1][l]; }
        c = fv * c + iv * gv;
        h = ov * tanh_f(c);                     // redundant in both waves
        if (write_all) {
            if (w == 0)
                out[((size_t)seq * TT + t) * 128 + dir * 64 + l] = h;
        } else if (step == TT - 1 && w == 0) {
            out[(size_t)seq * 128 + dir * 64 + l] = h;
        }
        // no second barrier: next step writes gbuf[1-buf]; gbuf[buf] is only
        // rewritten after the NEXT barrier, which both waves reach after the
        // reads above.
    }
}

// ---------------------------------------------------------------------------
__global__ __launch_bounds__(256) void fc_kernel(
    const float* __restrict__ fin,   // [NSEQ][128]
    const float* __restrict__ fc_W,  // [128]
    const float* __restrict__ fc_b,  // [1]
    float* __restrict__ outp)        // [NSEQ]
{
    int s = blockIdx.x * 256 + threadIdx.x;
    const float* fr = fin + (size_t)s * 128;
    float acc = fc_b[0];
#pragma unroll
    for (int k4 = 0; k4 < 32; ++k4) {
        float4 fv = *(const float4*)&fr[k4 * 4];
        float4 wv2 = *(const float4*)&fc_W[k4 * 4];
        acc += fv.x * wv2.x + fv.y * wv2.y + fv.z * wv2.z + fv.w * wv2.w;
    }
    outp[s] = acc;
}

// ---------------------------------------------------------------------------
extern "C" void kernel_launch(void* const* d_in, const int* in_sizes, int n_in,
                              void* d_out, int out_size, void* d_ws, size_t ws_size,
                              hipStream_t stream) {
    const float* x       = (const float*)d_in[0];
    const float* adj     = (const float*)d_in[1];
    const float* gat0_W  = (const float*)d_in[2];
    const float* gat0_a  = (const float*)d_in[3];
    const float* gat0_g  = (const float*)d_in[4];
    const float* gat0_b  = (const float*)d_in[5];
    const float* gat1_W  = (const float*)d_in[6];
    const float* gat1_a  = (const float*)d_in[7];
    const float* gat1_g  = (const float*)d_in[8];
    const float* gat1_b  = (const float*)d_in[9];
    const float* res_W   = (const float*)d_in[10];
    const float* res_b   = (const float*)d_in[11];
    const float* alpha_g = (const float*)d_in[12];
    const float* l0_Wih  = (const float*)d_in[13];
    const float* l0_Whh  = (const float*)d_in[14];
    const float* l0_bih  = (const float*)d_in[15];
    const float* l0_bhh  = (const float*)d_in[16];
    const float* l1_Wih  = (const float*)d_in[17];
    const float* l1_Whh  = (const float*)d_in[18];
    const float* l1_bih  = (const float*)d_in[19];
    const float* l1_bhh  = (const float*)d_in[20];
    const float* fc_W    = (const float*)d_in[21];
    const float* fc_b    = (const float*)d_in[22];

    float* ws = (float*)d_ws;
    float* g0    = ws;                    // [M][N][64]
    float* g1    = ws + 4194304;          // [M][N][64]
    float* seq   = ws + 8388608;          // [B*N][T][64]
    float* xg    = ws + 12582912;         // [2][65536][256]
    float* fin   = ws + 46137344;         // [NSEQ][128]
    float* o1    = ws;                    // reuse g0+g1 [NSEQ][T][128]

    gat_kernel<32><<<MM, 256, 0, stream>>>(x, adj, gat0_W, gat0_a, gat0_g, gat0_b, g0);
    gat_kernel<64><<<MM, 256, 0, stream>>>(g0, adj, gat1_W, gat1_a, gat1_g, gat1_b, g1);
    combine_kernel<<<(BB*SS*NN)/4, 256, 0, stream>>>(x, g1, res_W, res_b, alpha_g, seq);
    xg_gemm_kernel<64><<<dim3(MROWS/256, 2, 2), 256, 0, stream>>>(seq, l0_Wih, l0_bih, l0_bhh, xg);
    lstm_pair_kernel<<<2*NSEQ, 128, 0, stream>>>(xg, l0_Whh, o1, 1);
    xg_gemm_kernel<128><<<dim3(MROWS/256, 2, 2), 256, 0, stream>>>(o1, l1_Wih, l1_bih, l1_bhh, xg);
    lstm_pair_kernel<<<2*NSEQ, 128, 0, stream>>>(xg, l1_Whh, fin, 0);
    fc_kernel<<<NSEQ/256, 256, 0, stream>>>(fin, fc_W, fc_b, (float*)d_out);
}